// Round 17
// baseline (264.808 us; speedup 1.0000x reference)
//
#include <hip/hip_runtime.h>
#include <hip/hip_bf16.h>

#define N_NODES 50000
#define N_EDGES 1600000
#define N_REL   20
#define N_BASIS 16
#define DIM     128
#define KTOT    ((N_REL + 1) * DIM)      // 2688 : Wt row stride (20 rels + self)

#define NBINS   (N_NODES * N_REL)        // 1,000,000 : key = dst*20 + r  (dst-major)
#define CB_BITS 10
#define KEYS_PER_CB (1 << CB_BITS)                            // 1024
#define NCB  ((NBINS + KEYS_PER_CB - 1) >> CB_BITS)           // 977
#define CAP  2048                                             // slack cap (exp 1638, +10 sigma)
#define EB   4096
#define SORT_BLOCKS ((N_EDGES + EB - 1) / EB)                 // 391
#define BKG  32                                               // GEMM K-tile (24 KB LDS dbuf)

// prep_place block-range bases
#define WT_TOTAL  (DIM * (N_REL + 1) * DIM)                   // 344064
#define WT_BLOCKS (WT_TOTAL / 256)                            // 1344
#define XB_BLOCKS (N_NODES * DIM / 8 / 256)                   // 3125
#define NT_BLOCKS ((N_NODES + 63) / 64)                       // 782
#define WT_BASE   SORT_BLOCKS
#define XB_BASE   (WT_BASE + WT_BLOCKS)
#define NT_BASE   (XB_BASE + XB_BLOCKS)
#define PP_GRID   (NT_BASE + NT_BLOCKS)                       // 5642

typedef __attribute__((ext_vector_type(8))) short          bf16x8;
typedef __attribute__((ext_vector_type(4))) float          f32x4;
typedef __attribute__((ext_vector_type(8))) unsigned short ushort8v;

static __device__ __forceinline__ unsigned short f2bf(float f) {
    union { float f; unsigned int u; } v; v.f = f;
    unsigned int r = (v.u + 0x7FFFu + ((v.u >> 16) & 1u)) >> 16;   // RNE
    return (unsigned short)r;
}
static __device__ __forceinline__ float bf2f(unsigned short s) {
    union { unsigned int u; float f; } v; v.u = ((unsigned int)s) << 16;
    return v.f;
}

// ---------- merged prep + slack-place (independent work, one dispatch) ----------
__global__ __launch_bounds__(256) void prep_place(const float* __restrict__ x,
                                                  const int* __restrict__ eidx,
                                                  const int* __restrict__ etype,
                                                  const float* __restrict__ bases,
                                                  const float* __restrict__ bw,
                                                  const float* __restrict__ selfW,
                                                  const float* __restrict__ norm,
                                                  unsigned short* __restrict__ Wt,
                                                  unsigned short* __restrict__ xb,
                                                  float* __restrict__ normT,
                                                  unsigned int* __restrict__ ccur,
                                                  unsigned int* __restrict__ ebuf) {
    __shared__ unsigned int h[NCB];
    __shared__ unsigned int cur[NCB];
    __shared__ float tile[64][21];
    const int blk = blockIdx.x, tid = threadIdx.x;

    if (blk < SORT_BLOCKS) {                      // ---- place_slack ----
        for (int i = tid; i < NCB; i += 256) h[i] = 0;
        __syncthreads();
        int base = blk * EB;
        #pragma unroll
        for (int k = 0; k < EB / 256; ++k) {
            int e = base + k * 256 + tid;
            if (e < N_EDGES) {
                int key = eidx[N_EDGES + e] * N_REL + etype[e];
                atomicAdd(&h[key >> CB_BITS], 1u);
            }
        }
        __syncthreads();
        for (int i = tid; i < NCB; i += 256)
            cur[i] = atomicAdd(&ccur[i], h[i]);   // reserve private run
        __syncthreads();
        #pragma unroll
        for (int k = 0; k < EB / 256; ++k) {
            int e = base + k * 256 + tid;
            if (e < N_EDGES) {
                unsigned int src = (unsigned int)eidx[e];
                int key = eidx[N_EDGES + e] * N_REL + etype[e];
                int cb = key >> CB_BITS;
                unsigned int klo = (unsigned int)(key & (KEYS_PER_CB - 1));
                unsigned int pos = atomicAdd(&cur[cb], 1u);
                ebuf[(size_t)cb * CAP + pos] = (klo << 16) | src;
            }
        }
    } else if (blk < XB_BASE) {                   // ---- compute_wt ----
        int t = (blk - WT_BASE) * 256 + tid;
        int i = t & (DIM - 1);
        int r = (t >> 7) % (N_REL + 1);
        int o = t / (DIM * (N_REL + 1));
        float v;
        if (r < N_REL) {
            v = 0.f;
            #pragma unroll
            for (int b = 0; b < N_BASIS; ++b)
                v += bw[r * N_BASIS + b] * bases[((size_t)b * DIM + i) * DIM + o];
        } else {
            v = selfW[o * DIM + i];
        }
        Wt[(size_t)o * KTOT + r * DIM + i] = f2bf(v);
    } else if (blk < NT_BASE) {                   // ---- build_xb (x8 vectorized) ----
        int idx = (blk - XB_BASE) * 256 + tid;    // [0, 800000)
        const float4* x4 = (const float4*)x;
        float4 a = x4[idx * 2], b = x4[idx * 2 + 1];
        ushort8v o;
        o[0] = f2bf(a.x); o[1] = f2bf(a.y); o[2] = f2bf(a.z); o[3] = f2bf(a.w);
        o[4] = f2bf(b.x); o[5] = f2bf(b.y); o[6] = f2bf(b.z); o[7] = f2bf(b.w);
        *(ushort8v*)(xb + (size_t)idx * 8) = o;
    } else {                                      // ---- build_normT ----
        int d0 = (blk - NT_BASE) * 64;
        #pragma unroll
        for (int q = 0; q < 5; ++q) {
            int idx = q * 256 + tid;              // 1280 = 20 r x 64 d
            int r = idx >> 6, dc = idx & 63;
            if (r < N_REL && d0 + dc < N_NODES)
                tile[dc][r] = 1.0f / norm[(size_t)r * N_NODES + d0 + dc];
        }
        __syncthreads();
        #pragma unroll
        for (int q = 0; q < 5; ++q) {
            int idx = q * 256 + tid;
            int d = idx / 20, r = idx - d * 20;
            if (idx < 1280 && d0 + d < N_NODES)
                normT[(size_t)(d0 + d) * 20 + r] = tile[d][r];
        }
    }
}

// scan_fills: exclusive-scan the 977 bucket fills -> dense bases
__global__ __launch_bounds__(1024) void scan_fills(const unsigned int* __restrict__ ccur,
                                                   unsigned int* __restrict__ cbase,
                                                   unsigned int* __restrict__ binstart) {
    __shared__ unsigned int lds[1024];
    int t = threadIdx.x;
    unsigned int v = (t < NCB) ? ccur[t] : 0u;
    lds[t] = v; __syncthreads();
    for (int off = 1; off < 1024; off <<= 1) {
        unsigned int a = (t >= off) ? lds[t - off] : 0u;
        __syncthreads();
        lds[t] += a;
        __syncthreads();
    }
    unsigned int excl = lds[t] - v;
    if (t < NCB) cbase[t] = excl;
    if (t == NCB - 1) cbase[NCB] = lds[t];        // == N_EDGES
    if (t == 0) binstart[NBINS] = N_EDGES;        // global sentinel
}

// place_fine: 1024 threads, 1 key per thread (977 blocks -> full CU coverage)
__global__ __launch_bounds__(1024) void place_fine(const unsigned int* __restrict__ cbase,
                                                   const unsigned int* __restrict__ ccur,
                                                   const unsigned int* __restrict__ ebuf,
                                                   unsigned int* __restrict__ sorted,
                                                   unsigned int* __restrict__ binstart) {
    __shared__ unsigned int h[KEYS_PER_CB];
    __shared__ unsigned int cur[KEYS_PER_CB];
    __shared__ unsigned int pscan[1024];
    int b = blockIdx.x, t = threadIdx.x;
    unsigned int fill = ccur[b];
    unsigned int s = cbase[b];                    // dense base in sorted
    const unsigned int* src = ebuf + (size_t)b * CAP;
    h[t] = 0;
    __syncthreads();
    for (unsigned int j = t; j < fill; j += 1024)
        atomicAdd(&h[src[j] >> 16], 1u);
    __syncthreads();
    unsigned int c0 = h[t];
    pscan[t] = c0; __syncthreads();
    for (int off = 1; off < 1024; off <<= 1) {
        unsigned int a = (t >= off) ? pscan[t - off] : 0u;
        __syncthreads();
        pscan[t] += a;
        __syncthreads();
    }
    unsigned int run = pscan[t] - c0;             // exclusive within bucket
    int key = b * KEYS_PER_CB + t;
    if (key < NBINS) binstart[key] = s + run;
    cur[t] = run;
    __syncthreads();
    for (unsigned int j = t; j < fill; j += 1024) {
        unsigned int v = src[j];
        unsigned int klo = v >> 16;
        unsigned int key2 = (unsigned int)b * KEYS_PER_CB + klo;
        unsigned int r = key2 % N_REL;            // rel from key (magic-mul div)
        unsigned int pos = s + atomicAdd(&cur[klo], 1u);
        sorted[pos] = (r << 16) | (v & 0xFFFFu);  // payload: rel | src
    }
}

// ---------- reduce: wave per dst, register-resident edge stream, 16-wide load pipeline ----------
__global__ __launch_bounds__(256) void reduce_all(const unsigned int* __restrict__ sorted,
                                                  const unsigned int* __restrict__ binstart,
                                                  const unsigned int* __restrict__ xb32,
                                                  const float* __restrict__ normT,
                                                  unsigned int* __restrict__ agg32,
                                                  int r0, int rch, int rowK2) {
    int wv = threadIdx.x >> 6, lane = threadIdx.x & 63;
    int dst = blockIdx.x * 4 + wv;
    if (dst >= N_NODES) return;
    unsigned int nbase = (unsigned int)dst * N_REL;
    int rE  = r0 + rch;                          // exclusive end (may include slot 20 = self)
    int rEe = (rE < N_REL) ? rE : N_REL;         // exclusive end of edge-rels

    float nrm = (lane < rEe - r0) ? normT[nbase + r0 + lane] : 0.f;
    unsigned int bs = binstart[nbase + r0];
    unsigned int be = binstart[nbase + rEe];

    int cur_r = r0;
    float a0 = 0.f, a1 = 0.f;
    unsigned int pk, zz;
    asm("v_cvt_pk_bf16_f32 %0, %1, %2" : "=v"(zz) : "v"(0.f), "v"(0.f));

    #define FLUSH_ROW(RR, PKV) \
        agg32[(size_t)dst * rowK2 + ((RR) - r0) * 64 + lane] = (PKV)

    #define PROCESS(E, W) do {                                               \
        int rr_ = (int)((E) >> 16);                                          \
        if (rr_ != cur_r) {                                                  \
            float inv_ = __shfl(nrm, cur_r - r0);                            \
            float s0_ = a0 * inv_, s1_ = a1 * inv_;                          \
            asm("v_cvt_pk_bf16_f32 %0, %1, %2" : "=v"(pk) : "v"(s0_), "v"(s1_)); \
            FLUSH_ROW(cur_r, pk);                                            \
            for (int z_ = cur_r + 1; z_ < rr_; ++z_) FLUSH_ROW(z_, zz);      \
            a0 = 0.f; a1 = 0.f; cur_r = rr_;                                 \
        }                                                                    \
        a0 += bf2f((unsigned short)((W) & 0xFFFF));                          \
        a1 += bf2f((unsigned short)((W) >> 16));                             \
    } while (0)

    #define GATH(E) xb32[(size_t)((E) & 0xFFFF) * 64 + lane]

    for (unsigned int j = bs; j < be; ) {
        unsigned int rem = be - j;
        int chunk = (rem < 64u) ? (int)rem : 64;
        unsigned int ent = (lane < chunk) ? sorted[j + lane] : 0u;  // wave-wide metadata load
        int u = 0;
        for (; u + 16 <= chunk; u += 16) {       // 16 independent gathers in flight
            unsigned int e0 = __shfl(ent, u),      e1 = __shfl(ent, u + 1);
            unsigned int e2 = __shfl(ent, u + 2),  e3 = __shfl(ent, u + 3);
            unsigned int e4 = __shfl(ent, u + 4),  e5 = __shfl(ent, u + 5);
            unsigned int e6 = __shfl(ent, u + 6),  e7 = __shfl(ent, u + 7);
            unsigned int e8 = __shfl(ent, u + 8),  e9 = __shfl(ent, u + 9);
            unsigned int eA = __shfl(ent, u + 10), eB = __shfl(ent, u + 11);
            unsigned int eC = __shfl(ent, u + 12), eD = __shfl(ent, u + 13);
            unsigned int eE = __shfl(ent, u + 14), eF = __shfl(ent, u + 15);
            unsigned int w0 = GATH(e0), w1 = GATH(e1), w2 = GATH(e2), w3 = GATH(e3);
            unsigned int w4 = GATH(e4), w5 = GATH(e5), w6 = GATH(e6), w7 = GATH(e7);
            unsigned int w8 = GATH(e8), w9 = GATH(e9), wA = GATH(eA), wB = GATH(eB);
            unsigned int wC = GATH(eC), wD = GATH(eD), wE = GATH(eE), wF = GATH(eF);
            PROCESS(e0, w0); PROCESS(e1, w1); PROCESS(e2, w2); PROCESS(e3, w3);
            PROCESS(e4, w4); PROCESS(e5, w5); PROCESS(e6, w6); PROCESS(e7, w7);
            PROCESS(e8, w8); PROCESS(e9, w9); PROCESS(eA, wA); PROCESS(eB, wB);
            PROCESS(eC, wC); PROCESS(eD, wD); PROCESS(eE, wE); PROCESS(eF, wF);
        }
        for (; u + 8 <= chunk; u += 8) {         // 8-wide tail group
            unsigned int e0 = __shfl(ent, u),     e1 = __shfl(ent, u + 1);
            unsigned int e2 = __shfl(ent, u + 2), e3 = __shfl(ent, u + 3);
            unsigned int e4 = __shfl(ent, u + 4), e5 = __shfl(ent, u + 5);
            unsigned int e6 = __shfl(ent, u + 6), e7 = __shfl(ent, u + 7);
            unsigned int w0 = GATH(e0), w1 = GATH(e1), w2 = GATH(e2), w3 = GATH(e3);
            unsigned int w4 = GATH(e4), w5 = GATH(e5), w6 = GATH(e6), w7 = GATH(e7);
            PROCESS(e0, w0); PROCESS(e1, w1); PROCESS(e2, w2); PROCESS(e3, w3);
            PROCESS(e4, w4); PROCESS(e5, w5); PROCESS(e6, w6); PROCESS(e7, w7);
        }
        for (; u < chunk; ++u) {
            unsigned int e = __shfl(ent, u);
            unsigned int w = GATH(e);
            PROCESS(e, w);
        }
        j += chunk;
    }
    {
        float inv = __shfl(nrm, cur_r - r0);
        float s0 = a0 * inv, s1 = a1 * inv;
        asm("v_cvt_pk_bf16_f32 %0, %1, %2" : "=v"(pk) : "v"(s0), "v"(s1));
        FLUSH_ROW(cur_r, pk);
        for (int z = cur_r + 1; z < rEe; ++z) FLUSH_ROW(z, zz);
    }
    if (rE > N_REL) {                            // self-loop slot (virtual rel 20)
        unsigned int w = xb32[(size_t)dst * 64 + lane];
        float s0 = bf2f((unsigned short)(w & 0xFFFF));
        float s1 = bf2f((unsigned short)(w >> 16));
        asm("v_cvt_pk_bf16_f32 %0, %1, %2" : "=v"(pk) : "v"(s0), "v"(s1));
        agg32[(size_t)dst * rowK2 + (N_REL - r0) * 64 + lane] = pk;
    }
    #undef GATH
    #undef PROCESS
    #undef FLUSH_ROW
}

// ---------- MFMA GEMM: BK=32 dbuf (24 KB LDS -> 6 blocks/CU), counted vmcnt(3) ----------
// out[n][o] (+)= sum_k Wt_sub[o*KTOT+k] * Bsrc[n*K+k].  Tile: 64 n x 128 o.
// LDS rows = 32 shorts (64 B); 16B slot kq holds global chunk kq ^ swz(row),
// swz(row) = (row ^ row>>2) & 3  -> exact 2-way bank aliasing (free).
__global__ __launch_bounds__(256) void gemm_bf(const unsigned short* __restrict__ Wt_sub,
                                               const unsigned short* __restrict__ Bsrc,
                                               int K,
                                               float* __restrict__ C,
                                               int acc_mode) {
    __shared__ __align__(16) unsigned short WsL[2][128 * BKG];   // 16 KB
    __shared__ __align__(16) unsigned short AsL[2][64 * BKG];    // 8 KB

    const int tid  = threadIdx.x;
    const int lane = tid & 63;
    const int wv   = tid >> 6;
    const int wo   = wv >> 1;                    // o-half (0..1): 64 o rows
    const int wn   = wv & 1;                     // n-half (0..1): 32 n rows
    const int r16  = lane & 15;
    const int hi4  = lane >> 4;
    const int nb   = blockIdx.x * 64;

    #define SWZ(R) (((R) ^ ((R) >> 2)) & 3)

    // staging: per issue, wave fills 16 rows (lane>>2 = row-in-group, lane&3 = 16B slot)
    const int srow = lane >> 2;
    const int kq   = lane & 3;
    const unsigned short* sW[2];
    #pragma unroll
    for (int i = 0; i < 2; ++i) {
        int row = wv * 16 + i * 64 + srow;
        sW[i] = Wt_sub + (size_t)row * KTOT + ((kq ^ SWZ(row)) << 3);
    }
    const unsigned short* sA;
    {
        int row = wv * 16 + srow;
        int gn = nb + row; if (gn >= N_NODES) gn = N_NODES - 1;   // clamp (dup rows unused)
        sA = Bsrc + (size_t)gn * K + ((kq ^ SWZ(row)) << 3);
    }

    #define GL16(SRC, DST) __builtin_amdgcn_global_load_lds( \
        (const __attribute__((address_space(1))) void*)(SRC), \
        (__attribute__((address_space(3))) void*)(DST), 16, 0, 0)

    #define STAGE(B) do {                                                  \
        GL16(sW[0], &WsL[B][(wv * 16) * BKG]);                             \
        GL16(sW[1], &WsL[B][(wv * 16 + 64) * BKG]);                        \
        GL16(sA,    &AsL[B][(wv * 16) * BKG]);                             \
        sW[0] += BKG; sW[1] += BKG; sA += BKG;                             \
    } while (0)

    f32x4 acc[2][4];
    #pragma unroll
    for (int g = 0; g < 2; ++g)
        #pragma unroll
        for (int of = 0; of < 4; ++of) acc[g][of] = (f32x4){0.f, 0.f, 0.f, 0.f};

    const int NT = K / BKG;
    STAGE(0);                                    // tile 0 in flight

    int cur = 0;
    for (int t = 0; t < NT; ++t) {
        if (t + 1 < NT) {
            STAGE(cur ^ 1);                      // issue tile t+1 (3 loads; stay in flight)
            asm volatile("s_waitcnt vmcnt(3)" ::: "memory");   // tile t landed; t+1 pending
        } else {
            asm volatile("s_waitcnt vmcnt(0)" ::: "memory");
        }
        __builtin_amdgcn_s_barrier();            // all waves' tile-t DMA visible
        __builtin_amdgcn_sched_barrier(0);

        const unsigned short* Wb = WsL[cur];
        const unsigned short* Ab = AsL[cur];
        bf16x8 bfr[2];
        #pragma unroll
        for (int q = 0; q < 2; ++q) {
            int nr = wn * 32 + q * 16 + r16;
            bfr[q] = *(const bf16x8*)&Ab[nr * BKG + ((hi4 ^ SWZ(nr)) << 3)];
        }
        #pragma unroll
        for (int of = 0; of < 4; ++of) {
            int ro = wo * 64 + of * 16 + r16;
            bf16x8 afr = *(const bf16x8*)&Wb[ro * BKG + ((hi4 ^ SWZ(ro)) << 3)];
            acc[0][of] = __builtin_amdgcn_mfma_f32_16x16x32_bf16(afr, bfr[0], acc[0][of], 0, 0, 0);
            acc[1][of] = __builtin_amdgcn_mfma_f32_16x16x32_bf16(afr, bfr[1], acc[1][of], 0, 0, 0);
        }
        __builtin_amdgcn_sched_barrier(0);
        __builtin_amdgcn_s_barrier();            // reads of buf[cur] done before next STAGE(cur)
        cur ^= 1;
    }
    #undef STAGE
    #undef GL16
    #undef SWZ

    // epilogue: D col = r16 -> n, row = hi4*4+reg -> o (within frag)
    #pragma unroll
    for (int g = 0; g < 2; ++g) {
        int n = nb + wn * 32 + g * 16 + r16;
        if (n < N_NODES) {
            #pragma unroll
            for (int of = 0; of < 4; ++of) {
                float* p = C + (size_t)n * DIM + wo * 64 + of * 16 + hi4 * 4;
                if (acc_mode) {
                    p[0] += acc[g][of].x; p[1] += acc[g][of].y;
                    p[2] += acc[g][of].z; p[3] += acc[g][of].w;
                } else {
                    f32x4 v = acc[g][of];
                    *(float4*)p = (float4){v.x, v.y, v.z, v.w};
                }
            }
        }
    }
}

extern "C" void kernel_launch(void* const* d_in, const int* in_sizes, int n_in,
                              void* d_out, int out_size, void* d_ws, size_t ws_size,
                              hipStream_t stream) {
    const float* x     = (const float*)d_in[0];
    const int*   eidx  = (const int*)d_in[1];
    const int*   etype = (const int*)d_in[2];
    const float* norm  = (const float*)d_in[3];
    const float* selfW = (const float*)d_in[4];
    const float* bases = (const float*)d_in[5];
    const float* bw    = (const float*)d_in[6];
    float* out = (float*)d_out;

    // ---- workspace: fixed ~37 MB, agg takes the rest (chunked) ----
    char* p = (char*)d_ws;
    auto alloc = [&](size_t bytes) { char* q = p; p += (bytes + 255) & ~(size_t)255; return q; };
    unsigned short* Wt       = (unsigned short*)alloc((size_t)DIM * KTOT * 2);   // 0.69 MB
    unsigned short* xb       = (unsigned short*)alloc((size_t)N_NODES * DIM * 2);// 12.8 MB
    float*          normT    = (float*)alloc((size_t)N_NODES * N_REL * 4);       // 4.0 MB
    unsigned int*   sorted   = (unsigned int*)alloc((size_t)N_EDGES * 4);        // 6.4 MB
    unsigned int*   binstart = (unsigned int*)alloc((size_t)(NBINS + 1) * 4);    // 4.0 MB
    unsigned int*   ebuf     = (unsigned int*)alloc((size_t)NCB * CAP * 4);      // 8.0 MB slack
    unsigned int*   cbase    = (unsigned int*)alloc((size_t)(NCB + 1) * 4);
    unsigned int*   ccur     = (unsigned int*)alloc((size_t)NCB * 4);
    unsigned int*   agg32    = (unsigned int*)p;                                 // rest
    size_t fixed = (size_t)(p - (char*)d_ws);
    size_t per_rel = (size_t)N_NODES * DIM * 2;                                  // 12.8 MB
    // rch=11: 2 chunks; agg chunk = 141 MB, still L3-resident producer->consumer handoff
    int rch = 11;
    {
        size_t avail = (ws_size > fixed) ? ws_size - fixed : 0;
        int m = (int)(avail / per_rel);
        if (m < rch) rch = m;
        if (rch < 1) rch = 1;
    }

    // 1+2a. merged prep + slack-place (one dispatch; sort blocks scheduled first)
    hipMemsetAsync(ccur, 0, (size_t)NCB * 4, stream);
    prep_place<<<dim3(PP_GRID), dim3(256), 0, stream>>>(
        x, eidx, etype, bases, bw, selfW, norm, Wt, xb, normT, ccur, ebuf);

    // 2b. dense bases + fine place (977 blocks x 1024 threads)
    scan_fills<<<dim3(1), dim3(1024), 0, stream>>>(ccur, cbase, binstart);
    place_fine<<<dim3(NCB), dim3(1024), 0, stream>>>(cbase, ccur, ebuf, sorted, binstart);

    // 3. per chunk of rch rels (21 virtual rels incl. self): reduce + GEMM (L3-hot handoff)
    int gblocks = (N_NODES + 63) / 64;
    for (int r0 = 0; r0 < N_REL + 1; r0 += rch) {
        int rchA = (rch < N_REL + 1 - r0) ? rch : (N_REL + 1 - r0);
        reduce_all<<<dim3((N_NODES + 3) / 4), dim3(256), 0, stream>>>(
            sorted, binstart, (const unsigned int*)xb, normT, agg32, r0, rchA, rchA * 64);
        gemm_bf<<<dim3(gblocks), dim3(256), 0, stream>>>(
            Wt + r0 * DIM, (const unsigned short*)agg32, rchA * DIM, out, r0 > 0);
    }
}

// Round 18
// 256.252 us; speedup vs baseline: 1.0334x; 1.0334x over previous
//
#include <hip/hip_runtime.h>
#include <hip/hip_bf16.h>

#define N_NODES 50000
#define N_EDGES 1600000
#define N_REL   20
#define N_BASIS 16
#define DIM     128
#define KTOT    ((N_REL + 1) * DIM)      // 2688 : Wt row stride (20 rels + self)

#define NBINS   (N_NODES * N_REL)        // 1,000,000 : key = dst*20 + r  (dst-major)
#define CB_BITS 12
#define KEYS_PER_CB (1 << CB_BITS)                            // 4096
#define NCB  ((NBINS + KEYS_PER_CB - 1) >> CB_BITS)           // 245
#define CAP  8192                                             // slack bucket capacity (exp 6554)
#define EB   2048                                             // edges per sort block (782 blocks)
#define SORT_BLOCKS ((N_EDGES + EB - 1) / EB)                 // 782
#define BKG  32                                               // GEMM K-tile (24 KB LDS dbuf)

// prep_place block-range bases
#define WT_TOTAL  (DIM * (N_REL + 1) * DIM)                   // 344064
#define WT_BLOCKS (WT_TOTAL / 256)                            // 1344
#define XB_BLOCKS (N_NODES * DIM / 8 / 256)                   // 3125
#define NT_BLOCKS ((N_NODES + 63) / 64)                       // 782
#define WT_BASE   SORT_BLOCKS
#define XB_BASE   (WT_BASE + WT_BLOCKS)
#define NT_BASE   (XB_BASE + XB_BLOCKS)
#define PP_GRID   (NT_BASE + NT_BLOCKS)

typedef __attribute__((ext_vector_type(8))) short          bf16x8;
typedef __attribute__((ext_vector_type(4))) float          f32x4;
typedef __attribute__((ext_vector_type(8))) unsigned short ushort8v;

static __device__ __forceinline__ unsigned short f2bf(float f) {
    union { float f; unsigned int u; } v; v.f = f;
    unsigned int r = (v.u + 0x7FFFu + ((v.u >> 16) & 1u)) >> 16;   // RNE
    return (unsigned short)r;
}
static __device__ __forceinline__ float bf2f(unsigned short s) {
    union { unsigned int u; float f; } v; v.u = ((unsigned int)s) << 16;
    return v.f;
}

// ---------- merged prep + slack-place (independent work, one dispatch) ----------
__global__ __launch_bounds__(256) void prep_place(const float* __restrict__ x,
                                                  const int* __restrict__ eidx,
                                                  const int* __restrict__ etype,
                                                  const float* __restrict__ bases,
                                                  const float* __restrict__ bw,
                                                  const float* __restrict__ selfW,
                                                  const float* __restrict__ norm,
                                                  unsigned short* __restrict__ Wt,
                                                  unsigned short* __restrict__ xb,
                                                  float* __restrict__ normT,
                                                  unsigned int* __restrict__ ccur,
                                                  unsigned int* __restrict__ ebuf) {
    __shared__ unsigned int h[NCB];
    __shared__ unsigned int cur[NCB];
    __shared__ float tile[64][21];
    const int blk = blockIdx.x, tid = threadIdx.x;

    if (blk < SORT_BLOCKS) {                      // ---- place_slack (782 blocks, 2048 edges) ----
        for (int i = tid; i < NCB; i += 256) h[i] = 0;
        __syncthreads();
        int base = blk * EB;
        #pragma unroll
        for (int k = 0; k < EB / 256; ++k) {
            int e = base + k * 256 + tid;
            if (e < N_EDGES) {
                int key = eidx[N_EDGES + e] * N_REL + etype[e];
                atomicAdd(&h[key >> CB_BITS], 1u);
            }
        }
        __syncthreads();
        for (int i = tid; i < NCB; i += 256)
            cur[i] = atomicAdd(&ccur[i], h[i]);   // reserve private run
        __syncthreads();
        #pragma unroll
        for (int k = 0; k < EB / 256; ++k) {
            int e = base + k * 256 + tid;
            if (e < N_EDGES) {
                unsigned int src = (unsigned int)eidx[e];
                int key = eidx[N_EDGES + e] * N_REL + etype[e];
                int cb = key >> CB_BITS;
                unsigned int klo = (unsigned int)(key & (KEYS_PER_CB - 1));
                unsigned int pos = atomicAdd(&cur[cb], 1u);
                ebuf[(size_t)cb * CAP + pos] = (klo << 16) | src;
            }
        }
    } else if (blk < XB_BASE) {                   // ---- compute_wt ----
        int t = (blk - WT_BASE) * 256 + tid;
        int i = t & (DIM - 1);
        int r = (t >> 7) % (N_REL + 1);
        int o = t / (DIM * (N_REL + 1));
        float v;
        if (r < N_REL) {
            v = 0.f;
            #pragma unroll
            for (int b = 0; b < N_BASIS; ++b)
                v += bw[r * N_BASIS + b] * bases[((size_t)b * DIM + i) * DIM + o];
        } else {
            v = selfW[o * DIM + i];
        }
        Wt[(size_t)o * KTOT + r * DIM + i] = f2bf(v);
    } else if (blk < NT_BASE) {                   // ---- build_xb (x8 vectorized) ----
        int idx = (blk - XB_BASE) * 256 + tid;    // [0, 800000)
        const float4* x4 = (const float4*)x;
        float4 a = x4[idx * 2], b = x4[idx * 2 + 1];
        ushort8v o;
        o[0] = f2bf(a.x); o[1] = f2bf(a.y); o[2] = f2bf(a.z); o[3] = f2bf(a.w);
        o[4] = f2bf(b.x); o[5] = f2bf(b.y); o[6] = f2bf(b.z); o[7] = f2bf(b.w);
        *(ushort8v*)(xb + (size_t)idx * 8) = o;
    } else {                                      // ---- build_normT ----
        int d0 = (blk - NT_BASE) * 64;
        #pragma unroll
        for (int q = 0; q < 5; ++q) {
            int idx = q * 256 + tid;              // 1280 = 20 r x 64 d
            int r = idx >> 6, dc = idx & 63;
            if (r < N_REL && d0 + dc < N_NODES)
                tile[dc][r] = 1.0f / norm[(size_t)r * N_NODES + d0 + dc];
        }
        __syncthreads();
        #pragma unroll
        for (int q = 0; q < 5; ++q) {
            int idx = q * 256 + tid;
            int d = idx / 20, r = idx - d * 20;
            if (idx < 1280 && d0 + d < N_NODES)
                normT[(size_t)(d0 + d) * 20 + r] = tile[d][r];
        }
    }
}

// scan_fills: exclusive-scan the 245 bucket fills -> dense bases
__global__ __launch_bounds__(256) void scan_fills(const unsigned int* __restrict__ ccur,
                                                  unsigned int* __restrict__ cbase,
                                                  unsigned int* __restrict__ binstart) {
    __shared__ unsigned int lds[256];
    int t = threadIdx.x;
    unsigned int v = (t < NCB) ? ccur[t] : 0u;
    lds[t] = v; __syncthreads();
    for (int off = 1; off < 256; off <<= 1) {
        unsigned int a = (t >= off) ? lds[t - off] : 0u;
        __syncthreads();
        lds[t] += a;
        __syncthreads();
    }
    unsigned int excl = lds[t] - v;
    if (t < NCB) cbase[t] = excl;
    if (t == NCB - 1) cbase[NCB] = lds[t];        // == N_EDGES
    if (t == 0) binstart[NBINS] = N_EDGES;        // global sentinel
}

// place_fine: 1024 threads (245 blocks are CU-sparse; wider block = 4x issue slots)
__global__ __launch_bounds__(1024) void place_fine(const unsigned int* __restrict__ cbase,
                                                   const unsigned int* __restrict__ ccur,
                                                   const unsigned int* __restrict__ ebuf,
                                                   unsigned int* __restrict__ sorted,
                                                   unsigned int* __restrict__ binstart) {
    __shared__ unsigned int h[KEYS_PER_CB];
    __shared__ unsigned int cur[KEYS_PER_CB];
    __shared__ unsigned int pscan[1024];
    int b = blockIdx.x, t = threadIdx.x;
    unsigned int fill = ccur[b];
    unsigned int s = cbase[b];                    // dense base in sorted
    const unsigned int* src = ebuf + (size_t)b * CAP;
    #pragma unroll
    for (int q = 0; q < 4; ++q) h[t * 4 + q] = 0;
    __syncthreads();
    for (unsigned int j = t; j < fill; j += 1024)
        atomicAdd(&h[src[j] >> 16], 1u);
    __syncthreads();
    unsigned int c[4], part = 0;
    #pragma unroll
    for (int q = 0; q < 4; ++q) { c[q] = h[t * 4 + q]; part += c[q]; }
    pscan[t] = part; __syncthreads();
    for (int off = 1; off < 1024; off <<= 1) {
        unsigned int a = (t >= off) ? pscan[t - off] : 0u;
        __syncthreads();
        pscan[t] += a;
        __syncthreads();
    }
    unsigned int run = pscan[t] - part;
    #pragma unroll
    for (int q = 0; q < 4; ++q) {
        int key = b * KEYS_PER_CB + t * 4 + q;
        if (key < NBINS) binstart[key] = s + run;
        cur[t * 4 + q] = run;
        run += c[q];
    }
    __syncthreads();
    for (unsigned int j = t; j < fill; j += 1024) {
        unsigned int v = src[j];
        unsigned int klo = v >> 16;
        unsigned int key = (unsigned int)b * KEYS_PER_CB + klo;
        unsigned int r = key % N_REL;             // rel from key (magic-mul div)
        unsigned int pos = s + atomicAdd(&cur[klo], 1u);
        sorted[pos] = (r << 16) | (v & 0xFFFFu);  // payload: rel | src
    }
}

// ---------- reduce: wave per dst, register-resident edge stream, 8-wide load pipeline ----------
__global__ __launch_bounds__(256) void reduce_all(const unsigned int* __restrict__ sorted,
                                                  const unsigned int* __restrict__ binstart,
                                                  const unsigned int* __restrict__ xb32,
                                                  const float* __restrict__ normT,
                                                  unsigned int* __restrict__ agg32,
                                                  int r0, int rch, int rowK2) {
    int wv = threadIdx.x >> 6, lane = threadIdx.x & 63;
    int dst = blockIdx.x * 4 + wv;
    if (dst >= N_NODES) return;
    unsigned int nbase = (unsigned int)dst * N_REL;
    int rE  = r0 + rch;                          // exclusive end (may include slot 20 = self)
    int rEe = (rE < N_REL) ? rE : N_REL;         // exclusive end of edge-rels

    float nrm = (lane < rEe - r0) ? normT[nbase + r0 + lane] : 0.f;
    unsigned int bs = binstart[nbase + r0];
    unsigned int be = binstart[nbase + rEe];

    int cur_r = r0;
    float a0 = 0.f, a1 = 0.f;
    unsigned int pk, zz;
    asm("v_cvt_pk_bf16_f32 %0, %1, %2" : "=v"(zz) : "v"(0.f), "v"(0.f));

    #define FLUSH_ROW(RR, PKV) \
        agg32[(size_t)dst * rowK2 + ((RR) - r0) * 64 + lane] = (PKV)

    #define PROCESS(E, W) do {                                               \
        int rr_ = (int)((E) >> 16);                                          \
        if (rr_ != cur_r) {                                                  \
            float inv_ = __shfl(nrm, cur_r - r0);                            \
            float s0_ = a0 * inv_, s1_ = a1 * inv_;                          \
            asm("v_cvt_pk_bf16_f32 %0, %1, %2" : "=v"(pk) : "v"(s0_), "v"(s1_)); \
            FLUSH_ROW(cur_r, pk);                                            \
            for (int z_ = cur_r + 1; z_ < rr_; ++z_) FLUSH_ROW(z_, zz);      \
            a0 = 0.f; a1 = 0.f; cur_r = rr_;                                 \
        }                                                                    \
        a0 += bf2f((unsigned short)((W) & 0xFFFF));                          \
        a1 += bf2f((unsigned short)((W) >> 16));                             \
    } while (0)

    for (unsigned int j = bs; j < be; ) {
        unsigned int rem = be - j;
        int chunk = (rem < 64u) ? (int)rem : 64;
        unsigned int ent = (lane < chunk) ? sorted[j + lane] : 0u;  // wave-wide metadata load
        int u = 0;
        for (; u + 8 <= chunk; u += 8) {         // 8 independent gathers in flight
            unsigned int e0 = __shfl(ent, u),     e1 = __shfl(ent, u + 1);
            unsigned int e2 = __shfl(ent, u + 2), e3 = __shfl(ent, u + 3);
            unsigned int e4 = __shfl(ent, u + 4), e5 = __shfl(ent, u + 5);
            unsigned int e6 = __shfl(ent, u + 6), e7 = __shfl(ent, u + 7);
            unsigned int w0 = xb32[(size_t)(e0 & 0xFFFF) * 64 + lane];
            unsigned int w1 = xb32[(size_t)(e1 & 0xFFFF) * 64 + lane];
            unsigned int w2 = xb32[(size_t)(e2 & 0xFFFF) * 64 + lane];
            unsigned int w3 = xb32[(size_t)(e3 & 0xFFFF) * 64 + lane];
            unsigned int w4 = xb32[(size_t)(e4 & 0xFFFF) * 64 + lane];
            unsigned int w5 = xb32[(size_t)(e5 & 0xFFFF) * 64 + lane];
            unsigned int w6 = xb32[(size_t)(e6 & 0xFFFF) * 64 + lane];
            unsigned int w7 = xb32[(size_t)(e7 & 0xFFFF) * 64 + lane];
            PROCESS(e0, w0); PROCESS(e1, w1); PROCESS(e2, w2); PROCESS(e3, w3);
            PROCESS(e4, w4); PROCESS(e5, w5); PROCESS(e6, w6); PROCESS(e7, w7);
        }
        for (; u < chunk; ++u) {
            unsigned int e = __shfl(ent, u);
            unsigned int w = xb32[(size_t)(e & 0xFFFF) * 64 + lane];
            PROCESS(e, w);
        }
        j += chunk;
    }
    {
        float inv = __shfl(nrm, cur_r - r0);
        float s0 = a0 * inv, s1 = a1 * inv;
        asm("v_cvt_pk_bf16_f32 %0, %1, %2" : "=v"(pk) : "v"(s0), "v"(s1));
        FLUSH_ROW(cur_r, pk);
        for (int z = cur_r + 1; z < rEe; ++z) FLUSH_ROW(z, zz);
    }
    if (rE > N_REL) {                            // self-loop slot (virtual rel 20)
        unsigned int w = xb32[(size_t)dst * 64 + lane];
        float s0 = bf2f((unsigned short)(w & 0xFFFF));
        float s1 = bf2f((unsigned short)(w >> 16));
        asm("v_cvt_pk_bf16_f32 %0, %1, %2" : "=v"(pk) : "v"(s0), "v"(s1));
        agg32[(size_t)dst * rowK2 + (N_REL - r0) * 64 + lane] = pk;
    }
    #undef PROCESS
    #undef FLUSH_ROW
}

// ---------- MFMA GEMM: BK=32 dbuf (24 KB LDS -> 6 blocks/CU), counted vmcnt(3) ----------
// out[n][o] (+)= sum_k Wt_sub[o*KTOT+k] * Bsrc[n*K+k].  Tile: 64 n x 128 o.
// LDS rows = 32 shorts (64 B); 16B slot kq holds global chunk kq ^ swz(row),
// swz(row) = (row ^ row>>2) & 3  -> exact 2-way bank aliasing (free).
__global__ __launch_bounds__(256) void gemm_bf(const unsigned short* __restrict__ Wt_sub,
                                               const unsigned short* __restrict__ Bsrc,
                                               int K,
                                               float* __restrict__ C,
                                               int acc_mode) {
    __shared__ __align__(16) unsigned short WsL[2][128 * BKG];   // 16 KB
    __shared__ __align__(16) unsigned short AsL[2][64 * BKG];    // 8 KB

    const int tid  = threadIdx.x;
    const int lane = tid & 63;
    const int wv   = tid >> 6;
    const int wo   = wv >> 1;                    // o-half (0..1): 64 o rows
    const int wn   = wv & 1;                     // n-half (0..1): 32 n rows
    const int r16  = lane & 15;
    const int hi4  = lane >> 4;
    const int nb   = blockIdx.x * 64;

    #define SWZ(R) (((R) ^ ((R) >> 2)) & 3)

    // staging: per issue, wave fills 16 rows (lane>>2 = row-in-group, lane&3 = 16B slot)
    const int srow = lane >> 2;
    const int kq   = lane & 3;
    const unsigned short* sW[2];
    #pragma unroll
    for (int i = 0; i < 2; ++i) {
        int row = wv * 16 + i * 64 + srow;
        sW[i] = Wt_sub + (size_t)row * KTOT + ((kq ^ SWZ(row)) << 3);
    }
    const unsigned short* sA;
    {
        int row = wv * 16 + srow;
        int gn = nb + row; if (gn >= N_NODES) gn = N_NODES - 1;   // clamp (dup rows unused)
        sA = Bsrc + (size_t)gn * K + ((kq ^ SWZ(row)) << 3);
    }

    #define GL16(SRC, DST) __builtin_amdgcn_global_load_lds( \
        (const __attribute__((address_space(1))) void*)(SRC), \
        (__attribute__((address_space(3))) void*)(DST), 16, 0, 0)

    #define STAGE(B) do {                                                  \
        GL16(sW[0], &WsL[B][(wv * 16) * BKG]);                             \
        GL16(sW[1], &WsL[B][(wv * 16 + 64) * BKG]);                        \
        GL16(sA,    &AsL[B][(wv * 16) * BKG]);                             \
        sW[0] += BKG; sW[1] += BKG; sA += BKG;                             \
    } while (0)

    f32x4 acc[2][4];
    #pragma unroll
    for (int g = 0; g < 2; ++g)
        #pragma unroll
        for (int of = 0; of < 4; ++of) acc[g][of] = (f32x4){0.f, 0.f, 0.f, 0.f};

    const int NT = K / BKG;
    STAGE(0);                                    // tile 0 in flight

    int cur = 0;
    for (int t = 0; t < NT; ++t) {
        if (t + 1 < NT) {
            STAGE(cur ^ 1);                      // issue tile t+1 (3 loads; stay in flight)
            asm volatile("s_waitcnt vmcnt(3)" ::: "memory");   // tile t landed; t+1 pending
        } else {
            asm volatile("s_waitcnt vmcnt(0)" ::: "memory");
        }
        __builtin_amdgcn_s_barrier();            // all waves' tile-t DMA visible
        __builtin_amdgcn_sched_barrier(0);

        const unsigned short* Wb = WsL[cur];
        const unsigned short* Ab = AsL[cur];
        bf16x8 bfr[2];
        #pragma unroll
        for (int q = 0; q < 2; ++q) {
            int nr = wn * 32 + q * 16 + r16;
            bfr[q] = *(const bf16x8*)&Ab[nr * BKG + ((hi4 ^ SWZ(nr)) << 3)];
        }
        #pragma unroll
        for (int of = 0; of < 4; ++of) {
            int ro = wo * 64 + of * 16 + r16;
            bf16x8 afr = *(const bf16x8*)&Wb[ro * BKG + ((hi4 ^ SWZ(ro)) << 3)];
            acc[0][of] = __builtin_amdgcn_mfma_f32_16x16x32_bf16(afr, bfr[0], acc[0][of], 0, 0, 0);
            acc[1][of] = __builtin_amdgcn_mfma_f32_16x16x32_bf16(afr, bfr[1], acc[1][of], 0, 0, 0);
        }
        __builtin_amdgcn_sched_barrier(0);
        __builtin_amdgcn_s_barrier();            // reads of buf[cur] done before next STAGE(cur)
        cur ^= 1;
    }
    #undef STAGE
    #undef GL16
    #undef SWZ

    // epilogue: D col = r16 -> n, row = hi4*4+reg -> o (within frag)
    #pragma unroll
    for (int g = 0; g < 2; ++g) {
        int n = nb + wn * 32 + g * 16 + r16;
        if (n < N_NODES) {
            #pragma unroll
            for (int of = 0; of < 4; ++of) {
                float* p = C + (size_t)n * DIM + wo * 64 + of * 16 + hi4 * 4;
                if (acc_mode) {
                    p[0] += acc[g][of].x; p[1] += acc[g][of].y;
                    p[2] += acc[g][of].z; p[3] += acc[g][of].w;
                } else {
                    f32x4 v = acc[g][of];
                    *(float4*)p = (float4){v.x, v.y, v.z, v.w};
                }
            }
        }
    }
}

extern "C" void kernel_launch(void* const* d_in, const int* in_sizes, int n_in,
                              void* d_out, int out_size, void* d_ws, size_t ws_size,
                              hipStream_t stream) {
    const float* x     = (const float*)d_in[0];
    const int*   eidx  = (const int*)d_in[1];
    const int*   etype = (const int*)d_in[2];
    const float* norm  = (const float*)d_in[3];
    const float* selfW = (const float*)d_in[4];
    const float* bases = (const float*)d_in[5];
    const float* bw    = (const float*)d_in[6];
    float* out = (float*)d_out;

    // ---- workspace: fixed ~37 MB, agg takes the rest (chunked) ----
    char* p = (char*)d_ws;
    auto alloc = [&](size_t bytes) { char* q = p; p += (bytes + 255) & ~(size_t)255; return q; };
    unsigned short* Wt       = (unsigned short*)alloc((size_t)DIM * KTOT * 2);   // 0.69 MB
    unsigned short* xb       = (unsigned short*)alloc((size_t)N_NODES * DIM * 2);// 12.8 MB
    float*          normT    = (float*)alloc((size_t)N_NODES * N_REL * 4);       // 4.0 MB
    unsigned int*   sorted   = (unsigned int*)alloc((size_t)N_EDGES * 4);        // 6.4 MB
    unsigned int*   binstart = (unsigned int*)alloc((size_t)(NBINS + 1) * 4);    // 4.0 MB
    unsigned int*   ebuf     = (unsigned int*)alloc((size_t)NCB * CAP * 4);      // 8.0 MB slack
    unsigned int*   cbase    = (unsigned int*)alloc((size_t)(NCB + 1) * 4);
    unsigned int*   ccur     = (unsigned int*)alloc((size_t)NCB * 4);
    unsigned int*   agg32    = (unsigned int*)p;                                 // rest
    size_t fixed = (size_t)(p - (char*)d_ws);
    size_t per_rel = (size_t)N_NODES * DIM * 2;                                  // 12.8 MB
    // rch=11: 2 chunks; agg chunk = 141 MB, still L3-resident producer->consumer handoff
    int rch = 11;
    {
        size_t avail = (ws_size > fixed) ? ws_size - fixed : 0;
        int m = (int)(avail / per_rel);
        if (m < rch) rch = m;
        if (rch < 1) rch = 1;
    }

    // 1+2a. merged prep + slack-place (one dispatch; sort blocks scheduled first)
    hipMemsetAsync(ccur, 0, (size_t)NCB * 4, stream);
    prep_place<<<dim3(PP_GRID), dim3(256), 0, stream>>>(
        x, eidx, etype, bases, bw, selfW, norm, Wt, xb, normT, ccur, ebuf);

    // 2b. dense bases + fine place (wide blocks: 245 blocks are CU-sparse)
    scan_fills<<<dim3(1), dim3(256), 0, stream>>>(ccur, cbase, binstart);
    place_fine<<<dim3(NCB), dim3(1024), 0, stream>>>(cbase, ccur, ebuf, sorted, binstart);

    // 3. per chunk of rch rels (21 virtual rels incl. self): reduce + GEMM (L3-hot handoff)
    int gblocks = (N_NODES + 63) / 64;
    for (int r0 = 0; r0 < N_REL + 1; r0 += rch) {
        int rchA = (rch < N_REL + 1 - r0) ? rch : (N_REL + 1 - r0);
        reduce_all<<<dim3((N_NODES + 3) / 4), dim3(256), 0, stream>>>(
            sorted, binstart, (const unsigned int*)xb, normT, agg32, r0, rchA, rchA * 64);
        gemm_bf<<<dim3(gblocks), dim3(256), 0, stream>>>(
            Wt + r0 * DIM, (const unsigned short*)agg32, rchA * DIM, out, r0 > 0);
    }
}

// Round 19
// 236.461 us; speedup vs baseline: 1.1199x; 1.0837x over previous
//
#include <hip/hip_runtime.h>
#include <hip/hip_bf16.h>

#define N_NODES 50000
#define N_EDGES 1600000
#define N_REL   20
#define N_BASIS 16
#define DIM     128
#define KTOT    ((N_REL + 1) * DIM)      // 2688 : Wt row stride (20 rels + self)

#define NBINS   (N_NODES * N_REL)        // 1,000,000 : key = dst*20 + r  (dst-major)
#define CB_BITS 12
#define KEYS_PER_CB (1 << CB_BITS)                            // 4096
#define NCB  ((NBINS + KEYS_PER_CB - 1) >> CB_BITS)           // 245
#define CAP  8192                                             // slack bucket capacity (exp 6554)
#define EB   4096                                             // edges per sort block (391 blocks)
#define SORT_BLOCKS ((N_EDGES + EB - 1) / EB)                 // 391
#define BKG  32                                               // GEMM K-tile (24 KB LDS dbuf)

// prep_place block-range bases
#define WT_TOTAL  (DIM * (N_REL + 1) * DIM)                   // 344064
#define WT_BLOCKS (WT_TOTAL / 256)                            // 1344
#define XB_BLOCKS (N_NODES * DIM / 8 / 256)                   // 3125
#define NT_BLOCKS ((N_NODES + 63) / 64)                       // 782
#define WT_BASE   SORT_BLOCKS
#define XB_BASE   (WT_BASE + WT_BLOCKS)
#define NT_BASE   (XB_BASE + XB_BLOCKS)
#define PP_GRID   (NT_BASE + NT_BLOCKS)

typedef __attribute__((ext_vector_type(8))) short          bf16x8;
typedef __attribute__((ext_vector_type(4))) float          f32x4;
typedef __attribute__((ext_vector_type(8))) unsigned short ushort8v;

static __device__ __forceinline__ unsigned short f2bf(float f) {
    union { float f; unsigned int u; } v; v.f = f;
    unsigned int r = (v.u + 0x7FFFu + ((v.u >> 16) & 1u)) >> 16;   // RNE
    return (unsigned short)r;
}
static __device__ __forceinline__ float bf2f(unsigned short s) {
    union { unsigned int u; float f; } v; v.u = ((unsigned int)s) << 16;
    return v.f;
}

// ---------- merged prep + slack-place (independent work, one dispatch) ----------
__global__ __launch_bounds__(256) void prep_place(const float* __restrict__ x,
                                                  const int* __restrict__ eidx,
                                                  const int* __restrict__ etype,
                                                  const float* __restrict__ bases,
                                                  const float* __restrict__ bw,
                                                  const float* __restrict__ selfW,
                                                  const float* __restrict__ norm,
                                                  unsigned short* __restrict__ Wt,
                                                  unsigned short* __restrict__ xb,
                                                  float* __restrict__ normT,
                                                  unsigned int* __restrict__ ccur,
                                                  unsigned int* __restrict__ ebuf) {
    __shared__ unsigned int h[NCB];
    __shared__ unsigned int cur[NCB];
    __shared__ float tile[64][21];
    const int blk = blockIdx.x, tid = threadIdx.x;

    if (blk < SORT_BLOCKS) {                      // ---- place_slack ----
        for (int i = tid; i < NCB; i += 256) h[i] = 0;
        __syncthreads();
        int base = blk * EB;
        #pragma unroll
        for (int k = 0; k < EB / 256; ++k) {
            int e = base + k * 256 + tid;
            if (e < N_EDGES) {
                int key = eidx[N_EDGES + e] * N_REL + etype[e];
                atomicAdd(&h[key >> CB_BITS], 1u);
            }
        }
        __syncthreads();
        for (int i = tid; i < NCB; i += 256)
            cur[i] = atomicAdd(&ccur[i], h[i]);   // reserve private run
        __syncthreads();
        #pragma unroll
        for (int k = 0; k < EB / 256; ++k) {
            int e = base + k * 256 + tid;
            if (e < N_EDGES) {
                unsigned int src = (unsigned int)eidx[e];
                int key = eidx[N_EDGES + e] * N_REL + etype[e];
                int cb = key >> CB_BITS;
                unsigned int klo = (unsigned int)(key & (KEYS_PER_CB - 1));
                unsigned int pos = atomicAdd(&cur[cb], 1u);
                ebuf[(size_t)cb * CAP + pos] = (klo << 16) | src;
            }
        }
    } else if (blk < XB_BASE) {                   // ---- compute_wt (o = lane-fast: coalesced bases reads) ----
        int t = (blk - WT_BASE) * 256 + tid;
        int o = t & (DIM - 1);                    // lane-fast -> consecutive bases addresses
        int pair = t >> 7;                        // [0, 2688) = 21 r x 128 i
        int r = pair % (N_REL + 1);
        int i = pair / (N_REL + 1);
        float v;
        if (r < N_REL) {
            v = 0.f;
            #pragma unroll
            for (int b = 0; b < N_BASIS; ++b)
                v += bw[r * N_BASIS + b] * bases[((size_t)b * DIM + i) * DIM + o];
        } else {
            v = selfW[o * DIM + i];
        }
        Wt[(size_t)o * KTOT + r * DIM + i] = f2bf(v);   // scattered 2B store: L2-resident, cheap
    } else if (blk < NT_BASE) {                   // ---- build_xb (x8 vectorized) ----
        int idx = (blk - XB_BASE) * 256 + tid;    // [0, 800000)
        const float4* x4 = (const float4*)x;
        float4 a = x4[idx * 2], b = x4[idx * 2 + 1];
        ushort8v o;
        o[0] = f2bf(a.x); o[1] = f2bf(a.y); o[2] = f2bf(a.z); o[3] = f2bf(a.w);
        o[4] = f2bf(b.x); o[5] = f2bf(b.y); o[6] = f2bf(b.z); o[7] = f2bf(b.w);
        *(ushort8v*)(xb + (size_t)idx * 8) = o;
    } else {                                      // ---- build_normT ----
        int d0 = (blk - NT_BASE) * 64;
        #pragma unroll
        for (int q = 0; q < 5; ++q) {
            int idx = q * 256 + tid;              // 1280 = 20 r x 64 d
            int r = idx >> 6, dc = idx & 63;
            if (r < N_REL && d0 + dc < N_NODES)
                tile[dc][r] = 1.0f / norm[(size_t)r * N_NODES + d0 + dc];
        }
        __syncthreads();
        #pragma unroll
        for (int q = 0; q < 5; ++q) {
            int idx = q * 256 + tid;
            int d = idx / 20, r = idx - d * 20;
            if (idx < 1280 && d0 + d < N_NODES)
                normT[(size_t)(d0 + d) * 20 + r] = tile[d][r];
        }
    }
}

// scan_fills: exclusive-scan the 245 bucket fills -> dense bases
__global__ __launch_bounds__(256) void scan_fills(const unsigned int* __restrict__ ccur,
                                                  unsigned int* __restrict__ cbase,
                                                  unsigned int* __restrict__ binstart) {
    __shared__ unsigned int lds[256];
    int t = threadIdx.x;
    unsigned int v = (t < NCB) ? ccur[t] : 0u;
    lds[t] = v; __syncthreads();
    for (int off = 1; off < 256; off <<= 1) {
        unsigned int a = (t >= off) ? lds[t - off] : 0u;
        __syncthreads();
        lds[t] += a;
        __syncthreads();
    }
    unsigned int excl = lds[t] - v;
    if (t < NCB) cbase[t] = excl;
    if (t == NCB - 1) cbase[NCB] = lds[t];        // == N_EDGES
    if (t == 0) binstart[NBINS] = N_EDGES;        // global sentinel
}

// place_fine: 1024 threads (245 blocks are CU-sparse; wider block = 4x issue slots)
__global__ __launch_bounds__(1024) void place_fine(const unsigned int* __restrict__ cbase,
                                                   const unsigned int* __restrict__ ccur,
                                                   const unsigned int* __restrict__ ebuf,
                                                   unsigned int* __restrict__ sorted,
                                                   unsigned int* __restrict__ binstart) {
    __shared__ unsigned int h[KEYS_PER_CB];
    __shared__ unsigned int cur[KEYS_PER_CB];
    __shared__ unsigned int pscan[1024];
    int b = blockIdx.x, t = threadIdx.x;
    unsigned int fill = ccur[b];
    unsigned int s = cbase[b];                    // dense base in sorted
    const unsigned int* src = ebuf + (size_t)b * CAP;
    #pragma unroll
    for (int q = 0; q < 4; ++q) h[t * 4 + q] = 0;
    __syncthreads();
    for (unsigned int j = t; j < fill; j += 1024)
        atomicAdd(&h[src[j] >> 16], 1u);
    __syncthreads();
    unsigned int c[4], part = 0;
    #pragma unroll
    for (int q = 0; q < 4; ++q) { c[q] = h[t * 4 + q]; part += c[q]; }
    pscan[t] = part; __syncthreads();
    for (int off = 1; off < 1024; off <<= 1) {
        unsigned int a = (t >= off) ? pscan[t - off] : 0u;
        __syncthreads();
        pscan[t] += a;
        __syncthreads();
    }
    unsigned int run = pscan[t] - part;
    #pragma unroll
    for (int q = 0; q < 4; ++q) {
        int key = b * KEYS_PER_CB + t * 4 + q;
        if (key < NBINS) binstart[key] = s + run;
        cur[t * 4 + q] = run;
        run += c[q];
    }
    __syncthreads();
    for (unsigned int j = t; j < fill; j += 1024) {
        unsigned int v = src[j];
        unsigned int klo = v >> 16;
        unsigned int key = (unsigned int)b * KEYS_PER_CB + klo;
        unsigned int r = key % N_REL;             // rel from key (magic-mul div)
        unsigned int pos = s + atomicAdd(&cur[klo], 1u);
        sorted[pos] = (r << 16) | (v & 0xFFFFu);  // payload: rel | src
    }
}

// ---------- reduce: wave per dst, register-resident edge stream, 8-wide load pipeline ----------
__global__ __launch_bounds__(256) void reduce_all(const unsigned int* __restrict__ sorted,
                                                  const unsigned int* __restrict__ binstart,
                                                  const unsigned int* __restrict__ xb32,
                                                  const float* __restrict__ normT,
                                                  unsigned int* __restrict__ agg32,
                                                  int r0, int rch, int rowK2) {
    int wv = threadIdx.x >> 6, lane = threadIdx.x & 63;
    int dst = blockIdx.x * 4 + wv;
    if (dst >= N_NODES) return;
    unsigned int nbase = (unsigned int)dst * N_REL;
    int rE  = r0 + rch;                          // exclusive end (may include slot 20 = self)
    int rEe = (rE < N_REL) ? rE : N_REL;         // exclusive end of edge-rels

    float nrm = (lane < rEe - r0) ? normT[nbase + r0 + lane] : 0.f;
    unsigned int bs = binstart[nbase + r0];
    unsigned int be = binstart[nbase + rEe];

    int cur_r = r0;
    float a0 = 0.f, a1 = 0.f;
    unsigned int pk, zz;
    asm("v_cvt_pk_bf16_f32 %0, %1, %2" : "=v"(zz) : "v"(0.f), "v"(0.f));

    #define FLUSH_ROW(RR, PKV) \
        agg32[(size_t)dst * rowK2 + ((RR) - r0) * 64 + lane] = (PKV)

    #define PROCESS(E, W) do {                                               \
        int rr_ = (int)((E) >> 16);                                          \
        if (rr_ != cur_r) {                                                  \
            float inv_ = __shfl(nrm, cur_r - r0);                            \
            float s0_ = a0 * inv_, s1_ = a1 * inv_;                          \
            asm("v_cvt_pk_bf16_f32 %0, %1, %2" : "=v"(pk) : "v"(s0_), "v"(s1_)); \
            FLUSH_ROW(cur_r, pk);                                            \
            for (int z_ = cur_r + 1; z_ < rr_; ++z_) FLUSH_ROW(z_, zz);      \
            a0 = 0.f; a1 = 0.f; cur_r = rr_;                                 \
        }                                                                    \
        a0 += bf2f((unsigned short)((W) & 0xFFFF));                          \
        a1 += bf2f((unsigned short)((W) >> 16));                             \
    } while (0)

    for (unsigned int j = bs; j < be; ) {
        unsigned int rem = be - j;
        int chunk = (rem < 64u) ? (int)rem : 64;
        unsigned int ent = (lane < chunk) ? sorted[j + lane] : 0u;  // wave-wide metadata load
        int u = 0;
        for (; u + 8 <= chunk; u += 8) {         // 8 independent gathers in flight
            unsigned int e0 = __shfl(ent, u),     e1 = __shfl(ent, u + 1);
            unsigned int e2 = __shfl(ent, u + 2), e3 = __shfl(ent, u + 3);
            unsigned int e4 = __shfl(ent, u + 4), e5 = __shfl(ent, u + 5);
            unsigned int e6 = __shfl(ent, u + 6), e7 = __shfl(ent, u + 7);
            unsigned int w0 = xb32[(size_t)(e0 & 0xFFFF) * 64 + lane];
            unsigned int w1 = xb32[(size_t)(e1 & 0xFFFF) * 64 + lane];
            unsigned int w2 = xb32[(size_t)(e2 & 0xFFFF) * 64 + lane];
            unsigned int w3 = xb32[(size_t)(e3 & 0xFFFF) * 64 + lane];
            unsigned int w4 = xb32[(size_t)(e4 & 0xFFFF) * 64 + lane];
            unsigned int w5 = xb32[(size_t)(e5 & 0xFFFF) * 64 + lane];
            unsigned int w6 = xb32[(size_t)(e6 & 0xFFFF) * 64 + lane];
            unsigned int w7 = xb32[(size_t)(e7 & 0xFFFF) * 64 + lane];
            PROCESS(e0, w0); PROCESS(e1, w1); PROCESS(e2, w2); PROCESS(e3, w3);
            PROCESS(e4, w4); PROCESS(e5, w5); PROCESS(e6, w6); PROCESS(e7, w7);
        }
        for (; u < chunk; ++u) {
            unsigned int e = __shfl(ent, u);
            unsigned int w = xb32[(size_t)(e & 0xFFFF) * 64 + lane];
            PROCESS(e, w);
        }
        j += chunk;
    }
    {
        float inv = __shfl(nrm, cur_r - r0);
        float s0 = a0 * inv, s1 = a1 * inv;
        asm("v_cvt_pk_bf16_f32 %0, %1, %2" : "=v"(pk) : "v"(s0), "v"(s1));
        FLUSH_ROW(cur_r, pk);
        for (int z = cur_r + 1; z < rEe; ++z) FLUSH_ROW(z, zz);
    }
    if (rE > N_REL) {                            // self-loop slot (virtual rel 20)
        unsigned int w = xb32[(size_t)dst * 64 + lane];
        float s0 = bf2f((unsigned short)(w & 0xFFFF));
        float s1 = bf2f((unsigned short)(w >> 16));
        asm("v_cvt_pk_bf16_f32 %0, %1, %2" : "=v"(pk) : "v"(s0), "v"(s1));
        agg32[(size_t)dst * rowK2 + (N_REL - r0) * 64 + lane] = pk;
    }
    #undef PROCESS
    #undef FLUSH_ROW
}

// ---------- MFMA GEMM: BK=32 dbuf (24 KB LDS -> 6 blocks/CU), counted vmcnt(3) ----------
// out[n][o] (+)= sum_k Wt_sub[o*KTOT+k] * Bsrc[n*K+k].  Tile: 64 n x 128 o.
// LDS rows = 32 shorts (64 B); 16B slot kq holds global chunk kq ^ swz(row),
// swz(row) = (row ^ row>>2) & 3  -> exact 2-way bank aliasing (free).
__global__ __launch_bounds__(256) void gemm_bf(const unsigned short* __restrict__ Wt_sub,
                                               const unsigned short* __restrict__ Bsrc,
                                               int K,
                                               float* __restrict__ C,
                                               int acc_mode) {
    __shared__ __align__(16) unsigned short WsL[2][128 * BKG];   // 16 KB
    __shared__ __align__(16) unsigned short AsL[2][64 * BKG];    // 8 KB

    const int tid  = threadIdx.x;
    const int lane = tid & 63;
    const int wv   = tid >> 6;
    const int wo   = wv >> 1;                    // o-half (0..1): 64 o rows
    const int wn   = wv & 1;                     // n-half (0..1): 32 n rows
    const int r16  = lane & 15;
    const int hi4  = lane >> 4;
    const int nb   = blockIdx.x * 64;

    #define SWZ(R) (((R) ^ ((R) >> 2)) & 3)

    // staging: per issue, wave fills 16 rows (lane>>2 = row-in-group, lane&3 = 16B slot)
    const int srow = lane >> 2;
    const int kq   = lane & 3;
    const unsigned short* sW[2];
    #pragma unroll
    for (int i = 0; i < 2; ++i) {
        int row = wv * 16 + i * 64 + srow;
        sW[i] = Wt_sub + (size_t)row * KTOT + ((kq ^ SWZ(row)) << 3);
    }
    const unsigned short* sA;
    {
        int row = wv * 16 + srow;
        int gn = nb + row; if (gn >= N_NODES) gn = N_NODES - 1;   // clamp (dup rows unused)
        sA = Bsrc + (size_t)gn * K + ((kq ^ SWZ(row)) << 3);
    }

    #define GL16(SRC, DST) __builtin_amdgcn_global_load_lds( \
        (const __attribute__((address_space(1))) void*)(SRC), \
        (__attribute__((address_space(3))) void*)(DST), 16, 0, 0)

    #define STAGE(B) do {                                                  \
        GL16(sW[0], &WsL[B][(wv * 16) * BKG]);                             \
        GL16(sW[1], &WsL[B][(wv * 16 + 64) * BKG]);                        \
        GL16(sA,    &AsL[B][(wv * 16) * BKG]);                             \
        sW[0] += BKG; sW[1] += BKG; sA += BKG;                             \
    } while (0)

    f32x4 acc[2][4];
    #pragma unroll
    for (int g = 0; g < 2; ++g)
        #pragma unroll
        for (int of = 0; of < 4; ++of) acc[g][of] = (f32x4){0.f, 0.f, 0.f, 0.f};

    const int NT = K / BKG;
    STAGE(0);                                    // tile 0 in flight

    int cur = 0;
    for (int t = 0; t < NT; ++t) {
        if (t + 1 < NT) {
            STAGE(cur ^ 1);                      // issue tile t+1 (3 loads; stay in flight)
            asm volatile("s_waitcnt vmcnt(3)" ::: "memory");   // tile t landed; t+1 pending
        } else {
            asm volatile("s_waitcnt vmcnt(0)" ::: "memory");
        }
        __builtin_amdgcn_s_barrier();            // all waves' tile-t DMA visible
        __builtin_amdgcn_sched_barrier(0);

        const unsigned short* Wb = WsL[cur];
        const unsigned short* Ab = AsL[cur];
        bf16x8 bfr[2];
        #pragma unroll
        for (int q = 0; q < 2; ++q) {
            int nr = wn * 32 + q * 16 + r16;
            bfr[q] = *(const bf16x8*)&Ab[nr * BKG + ((hi4 ^ SWZ(nr)) << 3)];
        }
        #pragma unroll
        for (int of = 0; of < 4; ++of) {
            int ro = wo * 64 + of * 16 + r16;
            bf16x8 afr = *(const bf16x8*)&Wb[ro * BKG + ((hi4 ^ SWZ(ro)) << 3)];
            acc[0][of] = __builtin_amdgcn_mfma_f32_16x16x32_bf16(afr, bfr[0], acc[0][of], 0, 0, 0);
            acc[1][of] = __builtin_amdgcn_mfma_f32_16x16x32_bf16(afr, bfr[1], acc[1][of], 0, 0, 0);
        }
        __builtin_amdgcn_sched_barrier(0);
        __builtin_amdgcn_s_barrier();            // reads of buf[cur] done before next STAGE(cur)
        cur ^= 1;
    }
    #undef STAGE
    #undef GL16
    #undef SWZ

    // epilogue: D col = r16 -> n, row = hi4*4+reg -> o (within frag)
    #pragma unroll
    for (int g = 0; g < 2; ++g) {
        int n = nb + wn * 32 + g * 16 + r16;
        if (n < N_NODES) {
            #pragma unroll
            for (int of = 0; of < 4; ++of) {
                float* p = C + (size_t)n * DIM + wo * 64 + of * 16 + hi4 * 4;
                if (acc_mode) {
                    p[0] += acc[g][of].x; p[1] += acc[g][of].y;
                    p[2] += acc[g][of].z; p[3] += acc[g][of].w;
                } else {
                    f32x4 v = acc[g][of];
                    *(float4*)p = (float4){v.x, v.y, v.z, v.w};
                }
            }
        }
    }
}

extern "C" void kernel_launch(void* const* d_in, const int* in_sizes, int n_in,
                              void* d_out, int out_size, void* d_ws, size_t ws_size,
                              hipStream_t stream) {
    const float* x     = (const float*)d_in[0];
    const int*   eidx  = (const int*)d_in[1];
    const int*   etype = (const int*)d_in[2];
    const float* norm  = (const float*)d_in[3];
    const float* selfW = (const float*)d_in[4];
    const float* bases = (const float*)d_in[5];
    const float* bw    = (const float*)d_in[6];
    float* out = (float*)d_out;

    // ---- workspace: fixed ~37 MB, agg takes the rest (chunked) ----
    char* p = (char*)d_ws;
    auto alloc = [&](size_t bytes) { char* q = p; p += (bytes + 255) & ~(size_t)255; return q; };
    unsigned short* Wt       = (unsigned short*)alloc((size_t)DIM * KTOT * 2);   // 0.69 MB
    unsigned short* xb       = (unsigned short*)alloc((size_t)N_NODES * DIM * 2);// 12.8 MB
    float*          normT    = (float*)alloc((size_t)N_NODES * N_REL * 4);       // 4.0 MB
    unsigned int*   sorted   = (unsigned int*)alloc((size_t)N_EDGES * 4);        // 6.4 MB
    unsigned int*   binstart = (unsigned int*)alloc((size_t)(NBINS + 1) * 4);    // 4.0 MB
    unsigned int*   ebuf     = (unsigned int*)alloc((size_t)NCB * CAP * 4);      // 8.0 MB slack
    unsigned int*   cbase    = (unsigned int*)alloc((size_t)(NCB + 1) * 4);
    unsigned int*   ccur     = (unsigned int*)alloc((size_t)NCB * 4);
    unsigned int*   agg32    = (unsigned int*)p;                                 // rest
    size_t fixed = (size_t)(p - (char*)d_ws);
    size_t per_rel = (size_t)N_NODES * DIM * 2;                                  // 12.8 MB
    // rch=11: 2 chunks; agg chunk = 141 MB, still L3-resident producer->consumer handoff
    int rch = 11;
    {
        size_t avail = (ws_size > fixed) ? ws_size - fixed : 0;
        int m = (int)(avail / per_rel);
        if (m < rch) rch = m;
        if (rch < 1) rch = 1;
    }

    // 1+2a. merged prep + slack-place (one dispatch; sort blocks scheduled first)
    hipMemsetAsync(ccur, 0, (size_t)NCB * 4, stream);
    prep_place<<<dim3(PP_GRID), dim3(256), 0, stream>>>(
        x, eidx, etype, bases, bw, selfW, norm, Wt, xb, normT, ccur, ebuf);

    // 2b. dense bases + fine place (wide blocks: 245 blocks are CU-sparse)
    scan_fills<<<dim3(1), dim3(256), 0, stream>>>(ccur, cbase, binstart);
    place_fine<<<dim3(NCB), dim3(1024), 0, stream>>>(cbase, ccur, ebuf, sorted, binstart);

    // 3. per chunk of rch rels (21 virtual rels incl. self): reduce + GEMM (L3-hot handoff)
    int gblocks = (N_NODES + 63) / 64;
    for (int r0 = 0; r0 < N_REL + 1; r0 += rch) {
        int rchA = (rch < N_REL + 1 - r0) ? rch : (N_REL + 1 - r0);
        reduce_all<<<dim3((N_NODES + 3) / 4), dim3(256), 0, stream>>>(
            sorted, binstart, (const unsigned int*)xb, normT, agg32, r0, rchA, rchA * 64);
        gemm_bf<<<dim3(gblocks), dim3(256), 0, stream>>>(
            Wt + r0 * DIM, (const unsigned short*)agg32, rchA * DIM, out, r0 > 0);
    }
}